// Round 1
// baseline (148.211 us; speedup 1.0000x reference)
//
#include <hip/hip_runtime.h>
#include <hip/hip_fp16.h>

#define BB 32
#define HH 512
#define WW 512
#define PADK 15
#define RROWS 32
#define NSTRIPES (HH / RROWS)        // 16
#define NT 128                        // threads per block (2 waves)
#define NQ 128                        // float4-quads per row (WW/4)
#define NSTEPS (RROWS + 2 * PADK)     // 62
#define QPAD 4
#define NQP (NQ + 2 * QPAD)           // 136
#define NPIX_F 8388608.0f             // 32*512*512

// ws layout (floats): [0]=bce_sum, [1..32]=w_sum, [33..64]=inter, [65..96]=union

__global__ __launch_bounds__(NT)
void fused_pool_loss_kernel(const float* __restrict__ pred,
                            const float* __restrict__ targ,
                            float* __restrict__ ws)
{
    const int tid = threadIdx.x;
    const int b  = blockIdx.x / NSTRIPES;
    const int r0 = (blockIdx.x % NSTRIPES) * RROWS;

    // 31-row ring of horizontal 31-sums, fp16 (values in [0,31])
    __shared__ __half2 ring[31][NQ][2];          // 31744 B
    __shared__ float4  ebuf[2][NQP];             //  4352 B (double-buffered)
    __shared__ float   locq[2][NQP];             //  1088 B (quad sums)
    __shared__ float   red[2][4];

    // zero-init ring (we always subtract ring contents; window fills over 31 steps)
    {
        const __half2 z2 = __floats2half2_rn(0.f, 0.f);
        __half2* rp = &ring[0][0][0];
        for (int i = tid; i < 31 * NQ * 2; i += NT) rp[i] = z2;
    }
    // zero the horizontal halo pads (never written in the loop)
    if (tid < 2 * QPAD) {
        const int idx = (tid < QPAD) ? tid : (NQ + QPAD + (tid - QPAD));
        const float4 z4 = make_float4(0.f, 0.f, 0.f, 0.f);
        ebuf[0][idx] = z4; ebuf[1][idx] = z4;
        locq[0][idx] = 0.f; locq[1][idx] = 0.f;
    }
    __syncthreads();

    const float4* targ4 = (const float4*)(targ + (size_t)b * HH * WW);
    const float4* pred4 = (const float4*)(pred + (size_t)b * HH * WW);

    float vacc0 = 0.f, vacc1 = 0.f, vacc2 = 0.f, vacc3 = 0.f;
    float a_bce = 0.f, a_w = 0.f, a_i = 0.f, a_u = 0.f;
    int slot = 0;

    const float4 Z4 = make_float4(0.f, 0.f, 0.f, 0.f);
    auto ld_e = [&](int step) -> float4 {
        const int yy = r0 - PADK + step;
        if (yy < 0 || yy >= HH) return Z4;
        return targ4[yy * NQ + tid];
    };

    // software pipeline, depth 2
    float4 e_p0 = ld_e(0);
    float4 e_p1 = ld_e(1);
    float4 t_p0 = Z4, t_p1 = Z4, p_p0 = Z4, p_p1 = Z4;

    for (int step = 0; step < NSTEPS; ++step) {
        const float4 e = e_p0;
        e_p0 = e_p1;
        e_p1 = (step + 2 < NSTEPS) ? ld_e(step + 2) : Z4;

        const float4 tcur = t_p0, pcur = p_p0;
        t_p0 = t_p1; p_p0 = p_p1;
        {
            const int s2 = step + 2;
            if (s2 >= 2 * PADK && s2 < NSTEPS) {
                const int y = r0 + (s2 - 2 * PADK);
                t_p1 = targ4[y * NQ + tid];
                p_p1 = pred4[y * NQ + tid];
            }
        }

        const int bf = step & 1;
        ebuf[bf][tid + QPAD] = e;
        locq[bf][tid + QPAD] = e.x + e.y + e.z + e.w;
        __syncthreads();

        // horizontal 31-sums for this thread's 4 columns x = 4*tid + j
        float F = 0.f;
        #pragma unroll
        for (int k = -3; k <= 3; ++k) F += locq[bf][tid + QPAD + k];
        const float4 L = ebuf[bf][tid];             // quad tid-4 (cols 4t-16..4t-13)
        const float4 U = ebuf[bf][tid + 2 * QPAD];  // quad tid+4 (cols 4t+16..4t+19)
        const float h0 = F + L.y + L.z + L.w;           // [4t-15 .. 4t+15]
        const float h1 = F + L.z + L.w + U.x;           // [4t-14 .. 4t+16]
        const float h2 = F + L.w + U.x + U.y;           // [4t-13 .. 4t+17]
        const float h3 = F + U.x + U.y + U.z;           // [4t-12 .. 4t+18]

        // vertical sliding sum: add rounded value now, subtract SAME value 31 steps later
        const __half2 n01 = __floats2half2_rn(h0, h1);
        const __half2 n23 = __floats2half2_rn(h2, h3);
        const __half2 o01 = ring[slot][tid][0];
        const __half2 o23 = ring[slot][tid][1];
        ring[slot][tid][0] = n01;
        ring[slot][tid][1] = n23;
        const float2 nf01 = __half22float2(n01), nf23 = __half22float2(n23);
        const float2 of01 = __half22float2(o01), of23 = __half22float2(o23);
        vacc0 += nf01.x - of01.x;
        vacc1 += nf01.y - of01.y;
        vacc2 += nf23.x - of23.x;
        vacc3 += nf23.y - of23.y;
        slot = (slot == 30) ? 0 : (slot + 1);

        if (step >= 2 * PADK) {
            // output row y = r0 + step - 30; vacc covers rows [y-15, y+15]
            const float inv961 = (1.0f / 961.0f);
            const float tv[4] = {tcur.x, tcur.y, tcur.z, tcur.w};
            const float pv[4] = {pcur.x, pcur.y, pcur.z, pcur.w};
            const float va[4] = {vacc0, vacc1, vacc2, vacc3};
            #pragma unroll
            for (int j = 0; j < 4; ++j) {
                const float ap = va[j] * inv961;
                const float w  = fmaf(5.0f, fabsf(ap - tv[j]), 1.0f);
                const float pr = pv[j];
                const float ea = __expf(-fabsf(pr));          // exp(-|pr|)
                const float inv = __builtin_amdgcn_rcpf(1.0f + ea);
                const float p  = (pr >= 0.0f) ? inv : (1.0f - inv);   // sigmoid
                const float sp = fmaxf(pr, 0.0f) + __logf(1.0f + ea); // softplus
                a_bce += sp - pr * tv[j];
                a_w   += w;
                a_i   += p * tv[j] * w;
                a_u   += (p + tv[j]) * w;
            }
        }
    }

    // block reduction: wave shuffle then cross-wave via LDS
    #pragma unroll
    for (int off = 32; off > 0; off >>= 1) {
        a_bce += __shfl_down(a_bce, off, 64);
        a_w   += __shfl_down(a_w,   off, 64);
        a_i   += __shfl_down(a_i,   off, 64);
        a_u   += __shfl_down(a_u,   off, 64);
    }
    const int lane = tid & 63, wv = tid >> 6;
    if (lane == 0) { red[wv][0] = a_bce; red[wv][1] = a_w; red[wv][2] = a_i; red[wv][3] = a_u; }
    __syncthreads();
    if (tid == 0) {
        atomicAdd(&ws[0],      red[0][0] + red[1][0]);
        atomicAdd(&ws[1 + b],  red[0][1] + red[1][1]);
        atomicAdd(&ws[33 + b], red[0][2] + red[1][2]);
        atomicAdd(&ws[65 + b], red[0][3] + red[1][3]);
    }
}

__global__ void finalize_kernel(const float* __restrict__ ws, float* __restrict__ out)
{
    const int i = threadIdx.x;
    float val = 0.f;
    if (i < BB) {
        const float bce   = ws[0] * (1.0f / NPIX_F);
        const float wsum  = ws[1 + i];
        const float inter = ws[33 + i];
        const float uni   = ws[65 + i];
        const float w_bce = (wsum * bce + 1e-8f) / (wsum + 1e-8f);
        const float w_iou = 1.0f - (inter + 1.0f + 1e-8f) / (uni - inter + 1.0f + 1e-8f);
        val = w_bce + w_iou;
    }
    #pragma unroll
    for (int off = 32; off > 0; off >>= 1) val += __shfl_down(val, off, 64);
    if (i == 0) out[0] = val * (1.0f / BB);
}

extern "C" void kernel_launch(void* const* d_in, const int* in_sizes, int n_in,
                              void* d_out, int out_size, void* d_ws, size_t ws_size,
                              hipStream_t stream)
{
    (void)in_sizes; (void)n_in; (void)out_size; (void)ws_size;
    const float* pred = (const float*)d_in[0];   // y_pred
    const float* targ = (const float*)d_in[1];   // y_target
    float* out = (float*)d_out;
    float* ws  = (float*)d_ws;

    hipMemsetAsync(ws, 0, 97 * sizeof(float), stream);
    hipLaunchKernelGGL(fused_pool_loss_kernel, dim3(BB * NSTRIPES), dim3(NT), 0, stream,
                       pred, targ, ws);
    hipLaunchKernelGGL(finalize_kernel, dim3(1), dim3(64), 0, stream, ws, out);
}

// Round 2
// 139.823 us; speedup vs baseline: 1.0600x; 1.0600x over previous
//
#include <hip/hip_runtime.h>
#include <hip/hip_fp16.h>

#define BB 32
#define HH 512
#define WW 512
#define PADK 15
#define RROWS 32
#define NSTRIPES (HH / RROWS)     // 16
#define NCH 2                     // column halves
#define COLS (WW / NCH)           // 256 cols per block
#define NT 64                     // single wave per block
#define NQROW (WW / 4)            // 128 quads per full image row
#define CQ (COLS / 4)             // 64 quads per block core
#define QPAD 4                    // 4 halo quads (16 cols) each side
#define NQP (CQ + 2 * QPAD)       // 72
#define NSTEPS (RROWS + 2 * PADK) // 62
#define NPIX_F 8388608.0f         // 32*512*512

// ws layout (floats): [0]=bce_sum, [1..32]=w_sum, [33..64]=inter, [65..96]=union

__global__ __launch_bounds__(NT)
void fused_pool_loss_kernel(const float* __restrict__ pred,
                            const float* __restrict__ targ,
                            float* __restrict__ ws)
{
    const int lane = threadIdx.x;            // 0..63
    const int bi   = blockIdx.x;             // 1024 blocks
    const int half   = bi & 1;
    const int stripe = (bi >> 1) & (NSTRIPES - 1);
    const int b      = bi >> 5;              // image index
    const int r0  = stripe * RROWS;
    const int cq0 = half * CQ;               // first quad (col/4) of this block

    // 31-row ring of horizontal 31-sums, fp16. Layout [slot][c][lane]:
    // lane stride = 4B -> 2-way bank aliasing only (free on gfx950).
    __shared__ __half2 ring[31][2][NT];      // 15872 B
    __shared__ float4  ebuf[2][NQP];         //  2304 B
    __shared__ float   locq[2][NQP];         //   576 B

    // zero ring (values are always subtracted back out; window fills over 31 steps)
    {
        const __half2 z2 = __floats2half2_rn(0.f, 0.f);
        __half2* rp = &ring[0][0][0];
        for (int i = lane; i < 31 * 2 * NT; i += NT) rp[i] = z2;
    }
    __builtin_amdgcn_wave_barrier();

    const float4* targ4 = (const float4*)(targ + (size_t)b * HH * WW);
    const float4* pred4 = (const float4*)(pred + (size_t)b * HH * WW);

    const float4 Z4 = make_float4(0.f, 0.f, 0.f, 0.f);

    // halo quad index for lanes 0..7 (left: 4 quads before core, right: 4 after)
    const int hq = (lane < 4) ? (cq0 - QPAD + lane) : (cq0 + CQ + (lane - 4));
    const bool hq_ok = (lane < 8) && (hq >= 0) && (hq < NQROW);
    const int hslot = (lane < 4) ? lane : (CQ + QPAD + (lane - 4));

    auto ld_row = [&](int step, float4& m, float4& h) {
        m = Z4; h = Z4;
        const int yy = r0 - PADK + step;
        if (step < NSTEPS && yy >= 0 && yy < HH) {
            const float4* rp = targ4 + (size_t)yy * NQROW;
            m = rp[cq0 + lane];
            if (hq_ok) h = rp[hq];
        }
    };

    float vacc0 = 0.f, vacc1 = 0.f, vacc2 = 0.f, vacc3 = 0.f;
    float a_bce = 0.f, a_w = 0.f, a_i = 0.f, a_u = 0.f;
    int slot = 0;

    // software pipeline depth 2 — stays in flight (no s_barrier in the loop)
    float4 e_p0, e_p1, h_p0, h_p1;
    ld_row(0, e_p0, h_p0);
    ld_row(1, e_p1, h_p1);
    float4 t_p0 = Z4, t_p1 = Z4, p_p0 = Z4, p_p1 = Z4;

    for (int step = 0; step < NSTEPS; ++step) {
        const float4 e  = e_p0;  e_p0 = e_p1;
        const float4 eh = h_p0;  h_p0 = h_p1;
        ld_row(step + 2, e_p1, h_p1);

        const float4 tcur = t_p0, pcur = p_p0;
        t_p0 = t_p1; p_p0 = p_p1;
        {
            const int s2 = step + 2;
            if (s2 >= 2 * PADK && s2 < NSTEPS) {
                const size_t off = (size_t)(r0 + (s2 - 2 * PADK)) * NQROW + cq0 + lane;
                t_p1 = targ4[off];
                p_p1 = pred4[off];
            }
        }

        const int bf = step & 1;
        ebuf[bf][QPAD + lane] = e;
        locq[bf][QPAD + lane] = e.x + e.y + e.z + e.w;
        if (lane < 8) {
            ebuf[bf][hslot] = eh;
            locq[bf][hslot] = eh.x + eh.y + eh.z + eh.w;
        }
        __builtin_amdgcn_wave_barrier();   // compile-time fence; lgkmcnt ordering
                                           // is enforced by the memory legalizer

        // horizontal 31-sums for this lane's 4 columns x = c0 + 4*lane + j
        float F = 0.f;
        #pragma unroll
        for (int k = -3; k <= 3; ++k) F += locq[bf][lane + QPAD + k];
        const float4 L = ebuf[bf][lane];            // cols 4t-16..4t-13 (rel)
        const float4 U = ebuf[bf][lane + 2 * QPAD]; // cols 4t+16..4t+19 (rel)
        const float h0 = F + L.y + L.z + L.w;
        const float h1 = F + L.z + L.w + U.x;
        const float h2 = F + L.w + U.x + U.y;
        const float h3 = F + U.x + U.y + U.z;

        // vertical sliding sum: add rounded value now, subtract SAME value 31 steps later
        const __half2 n01 = __floats2half2_rn(h0, h1);
        const __half2 n23 = __floats2half2_rn(h2, h3);
        const __half2 o01 = ring[slot][0][lane];
        const __half2 o23 = ring[slot][1][lane];
        ring[slot][0][lane] = n01;
        ring[slot][1][lane] = n23;
        const float2 nf01 = __half22float2(n01), nf23 = __half22float2(n23);
        const float2 of01 = __half22float2(o01), of23 = __half22float2(o23);
        vacc0 += nf01.x - of01.x;
        vacc1 += nf01.y - of01.y;
        vacc2 += nf23.x - of23.x;
        vacc3 += nf23.y - of23.y;
        slot = (slot == 30) ? 0 : (slot + 1);

        if (step >= 2 * PADK) {
            const float inv961 = (1.0f / 961.0f);
            const float tv[4] = {tcur.x, tcur.y, tcur.z, tcur.w};
            const float pv[4] = {pcur.x, pcur.y, pcur.z, pcur.w};
            const float va[4] = {vacc0, vacc1, vacc2, vacc3};
            #pragma unroll
            for (int j = 0; j < 4; ++j) {
                const float ap = va[j] * inv961;
                const float w  = fmaf(5.0f, fabsf(ap - tv[j]), 1.0f);
                const float pr = pv[j];
                const float ea = __expf(-fabsf(pr));                  // exp(-|pr|)
                const float inv = __builtin_amdgcn_rcpf(1.0f + ea);
                const float p  = (pr >= 0.0f) ? inv : (1.0f - inv);   // sigmoid
                const float sp = fmaxf(pr, 0.0f) + __logf(1.0f + ea); // softplus
                a_bce += sp - pr * tv[j];
                a_w   += w;
                a_i   += p * tv[j] * w;
                a_u   += (p + tv[j]) * w;
            }
        }
    }

    // single-wave block: pure shuffle reduction, lane 0 does the atomics
    #pragma unroll
    for (int off = 32; off > 0; off >>= 1) {
        a_bce += __shfl_down(a_bce, off, 64);
        a_w   += __shfl_down(a_w,   off, 64);
        a_i   += __shfl_down(a_i,   off, 64);
        a_u   += __shfl_down(a_u,   off, 64);
    }
    if (lane == 0) {
        atomicAdd(&ws[0],      a_bce);
        atomicAdd(&ws[1 + b],  a_w);
        atomicAdd(&ws[33 + b], a_i);
        atomicAdd(&ws[65 + b], a_u);
    }
}

__global__ void finalize_kernel(const float* __restrict__ ws, float* __restrict__ out)
{
    const int i = threadIdx.x;
    float val = 0.f;
    if (i < BB) {
        const float bce   = ws[0] * (1.0f / NPIX_F);
        const float wsum  = ws[1 + i];
        const float inter = ws[33 + i];
        const float uni   = ws[65 + i];
        const float w_bce = (wsum * bce + 1e-8f) / (wsum + 1e-8f);
        const float w_iou = 1.0f - (inter + 1.0f + 1e-8f) / (uni - inter + 1.0f + 1e-8f);
        val = w_bce + w_iou;
    }
    #pragma unroll
    for (int off = 32; off > 0; off >>= 1) val += __shfl_down(val, off, 64);
    if (i == 0) out[0] = val * (1.0f / BB);
}

extern "C" void kernel_launch(void* const* d_in, const int* in_sizes, int n_in,
                              void* d_out, int out_size, void* d_ws, size_t ws_size,
                              hipStream_t stream)
{
    (void)in_sizes; (void)n_in; (void)out_size; (void)ws_size;
    const float* pred = (const float*)d_in[0];   // y_pred
    const float* targ = (const float*)d_in[1];   // y_target
    float* out = (float*)d_out;
    float* ws  = (float*)d_ws;

    hipMemsetAsync(ws, 0, 97 * sizeof(float), stream);
    hipLaunchKernelGGL(fused_pool_loss_kernel,
                       dim3(BB * NSTRIPES * NCH), dim3(NT), 0, stream,
                       pred, targ, ws);
    hipLaunchKernelGGL(finalize_kernel, dim3(1), dim3(64), 0, stream, ws, out);
}